// Round 1
// baseline (17.003 us; speedup 1.0000x reference)
//
#include <hip/hip_runtime.h>

#define BATCH 256
#define NV    5000
#define NCLS  20000
#define G     2           // batch rows per block (interleaved in LDS)
#define NT    256         // threads per block

// Evaluates sum_j f[j] * prod_s (bit_s(j) ? p_s : 1-p_s) via Horner factoring.
__device__ __forceinline__ float eval_clause(const float4& fa, const float4& fb,
                                             float p0, float p1, float p2) {
    float t0 = fa.x + (fa.y - fa.x) * p2;   // b0=0,b1=0
    float t1 = fa.z + (fa.w - fa.z) * p2;   // b0=0,b1=1
    float t2 = fb.x + (fb.y - fb.x) * p2;   // b0=1,b1=0
    float t3 = fb.z + (fb.w - fb.z) * p2;   // b0=1,b1=1
    float u0 = t0 + (t1 - t0) * p1;
    float u1 = t2 + (t3 - t2) * p1;
    return u0 + (u1 - u0) * p0;
}

// Block (bg, cs): batch rows [bg*G, bg*G+G), clause chunk cs.
// Writes partial sums to outbuf[cs*BATCH + b].
__global__ __launch_bounds__(NT)
void bmn_main(const float* __restrict__ x,
              const int*   __restrict__ vars,
              const float* __restrict__ factors,
              float* __restrict__ outbuf,
              int cchunk) {
    __shared__ float xs[NV * G];          // interleaved: xs[v*G + g]  (40 KB)
    const int bg  = blockIdx.x;
    const int cs  = blockIdx.y;
    const int tid = threadIdx.x;

    const float* row0 = x + (bg * G + 0) * NV;
    const float* row1 = x + (bg * G + 1) * NV;
    for (int i = tid; i < NV; i += NT) {
        float2 v2 = make_float2(row0[i], row1[i]);
        *reinterpret_cast<float2*>(&xs[i * 2]) = v2;   // 2-way bank alias: free
    }
    __syncthreads();

    float acc0 = 0.f, acc1 = 0.f;
    const int cbase = cs * cchunk;
    const int cend  = cbase + cchunk;
    for (int c = cbase + tid; c < cend; c += NT) {
        const int v0 = vars[c * 3 + 0];
        const int v1 = vars[c * 3 + 1];
        const int v2 = vars[c * 3 + 2];
        const float4 fa = *reinterpret_cast<const float4*>(factors + c * 8);
        const float4 fb = *reinterpret_cast<const float4*>(factors + c * 8 + 4);
        // one ds_read_b64 per variable fetches both batch rows' value
        const float2 p0 = *reinterpret_cast<const float2*>(&xs[v0 * 2]);
        const float2 p1 = *reinterpret_cast<const float2*>(&xs[v1 * 2]);
        const float2 p2 = *reinterpret_cast<const float2*>(&xs[v2 * 2]);
        acc0 += eval_clause(fa, fb, p0.x, p1.x, p2.x);
        acc1 += eval_clause(fa, fb, p0.y, p1.y, p2.y);
    }

    // reduce 256 threads -> 2 scalars
    for (int off = 32; off; off >>= 1) {
        acc0 += __shfl_down(acc0, off, 64);
        acc1 += __shfl_down(acc1, off, 64);
    }
    __shared__ float red[4][2];
    const int w = tid >> 6;
    if ((tid & 63) == 0) { red[w][0] = acc0; red[w][1] = acc1; }
    __syncthreads();
    if (tid == 0) {
        float s0 = red[0][0] + red[1][0] + red[2][0] + red[3][0];
        float s1 = red[0][1] + red[1][1] + red[2][1] + red[3][1];
        outbuf[cs * BATCH + bg * G + 0] = s0;
        outbuf[cs * BATCH + bg * G + 1] = s1;
    }
}

__global__ __launch_bounds__(BATCH)
void bmn_reduce(const float* __restrict__ ws, float* __restrict__ out) {
    const int b = threadIdx.x;
    out[b] = ws[b] + ws[BATCH + b];
}

extern "C" void kernel_launch(void* const* d_in, const int* in_sizes, int n_in,
                              void* d_out, int out_size, void* d_ws, size_t ws_size,
                              hipStream_t stream) {
    const float* x       = (const float*)d_in[0];
    // d_in[1] = binary_combinations (unused: hard-coded bit order)
    const int*   vars    = (const int*)d_in[2];
    const float* factors = (const float*)d_in[3];
    float* out = (float*)d_out;

    if (ws_size >= 2 * BATCH * sizeof(float)) {
        float* ws = (float*)d_ws;
        bmn_main<<<dim3(BATCH / G, 2), NT, 0, stream>>>(x, vars, factors, ws, NCLS / 2);
        bmn_reduce<<<1, BATCH, 0, stream>>>(ws, out);
    } else {
        // fallback: single chunk writes final sums directly
        bmn_main<<<dim3(BATCH / G, 1), NT, 0, stream>>>(x, vars, factors, out, NCLS);
    }
}

// Round 2
// 12.437 us; speedup vs baseline: 1.3672x; 1.3672x over previous
//
#include <hip/hip_runtime.h>

#define BATCH 256
#define NV    5000
#define NCLS  20000
#define G     4           // batch rows per block (interleaved by 4 in LDS)
#define NT    512         // threads per block (8 waves)
#define NCH   8           // clause chunks

// f-values with precomputed deltas; Horner over the 3 selector bits.
__device__ __forceinline__ float eval4(float f0, float d0, float f2, float d1,
                                       float f4, float d2, float f6, float d3,
                                       float p0, float p1, float p2) {
    float t0 = fmaf(d0, p2, f0);
    float t1 = fmaf(d1, p2, f2);
    float t2 = fmaf(d2, p2, f4);
    float t3 = fmaf(d3, p2, f6);
    float u0 = fmaf(t1 - t0, p1, t0);
    float u1 = fmaf(t3 - t2, p1, t2);
    return fmaf(u1 - u0, p0, u0);
}

// Block (bg, cs): batch rows [bg*G, bg*G+G), clause chunk cs of size cchunk.
// Partial sums -> outbuf[cs*BATCH + b].
__global__ __launch_bounds__(NT)
void bmn_main(const float* __restrict__ x,
              const int*   __restrict__ vars,
              const float* __restrict__ factors,
              float* __restrict__ outbuf,
              int cchunk) {
    __shared__ float xs[NV * G];          // 80 KB: xs[v*4 + g]
    const int bg  = blockIdx.x;
    const int cs  = blockIdx.y;
    const int tid = threadIdx.x;

    const float* xr = x + bg * G * NV;
    for (int i = tid; i < NV; i += NT) {
        float4 v;
        v.x = xr[i];
        v.y = xr[i + NV];
        v.z = xr[i + 2 * NV];
        v.w = xr[i + 3 * NV];
        *reinterpret_cast<float4*>(&xs[i * 4]) = v;
    }
    __syncthreads();

    float4 acc = make_float4(0.f, 0.f, 0.f, 0.f);
    const int cbase = cs * cchunk;
    const int cend  = cbase + cchunk;
    for (int c = cbase + tid; c < cend; c += NT) {
        const int v0 = vars[c * 3 + 0];
        const int v1 = vars[c * 3 + 1];
        const int v2 = vars[c * 3 + 2];
        const float4 fa = *reinterpret_cast<const float4*>(factors + c * 8);
        const float4 fb = *reinterpret_cast<const float4*>(factors + c * 8 + 4);
        // one ds_read_b128 per variable serves all 4 batch rows
        const float4 p0 = *reinterpret_cast<const float4*>(&xs[v0 * 4]);
        const float4 p1 = *reinterpret_cast<const float4*>(&xs[v1 * 4]);
        const float4 p2 = *reinterpret_cast<const float4*>(&xs[v2 * 4]);
        // first-level deltas shared across the 4 rows
        const float d0 = fa.y - fa.x, d1 = fa.w - fa.z;
        const float d2 = fb.y - fb.x, d3 = fb.w - fb.z;
        acc.x += eval4(fa.x, d0, fa.z, d1, fb.x, d2, fb.z, d3, p0.x, p1.x, p2.x);
        acc.y += eval4(fa.x, d0, fa.z, d1, fb.x, d2, fb.z, d3, p0.y, p1.y, p2.y);
        acc.z += eval4(fa.x, d0, fa.z, d1, fb.x, d2, fb.z, d3, p0.z, p1.z, p2.z);
        acc.w += eval4(fa.x, d0, fa.z, d1, fb.x, d2, fb.z, d3, p0.w, p1.w, p2.w);
    }

    // wave reduce (64 lanes)
    for (int off = 32; off; off >>= 1) {
        acc.x += __shfl_down(acc.x, off, 64);
        acc.y += __shfl_down(acc.y, off, 64);
        acc.z += __shfl_down(acc.z, off, 64);
        acc.w += __shfl_down(acc.w, off, 64);
    }
    __shared__ float red[NT / 64][G];
    if ((tid & 63) == 0) {
        const int w = tid >> 6;
        red[w][0] = acc.x; red[w][1] = acc.y; red[w][2] = acc.z; red[w][3] = acc.w;
    }
    __syncthreads();
    if (tid < G) {
        float s = 0.f;
        #pragma unroll
        for (int w = 0; w < NT / 64; ++w) s += red[w][tid];
        outbuf[cs * BATCH + bg * G + tid] = s;
    }
}

__global__ __launch_bounds__(BATCH)
void bmn_reduce(const float* __restrict__ ws, float* __restrict__ out) {
    const int b = threadIdx.x;
    float s = 0.f;
    #pragma unroll
    for (int cs = 0; cs < NCH; ++cs) s += ws[cs * BATCH + b];
    out[b] = s;
}

extern "C" void kernel_launch(void* const* d_in, const int* in_sizes, int n_in,
                              void* d_out, int out_size, void* d_ws, size_t ws_size,
                              hipStream_t stream) {
    const float* x       = (const float*)d_in[0];
    // d_in[1] = binary_combinations (unused: bit order hard-coded, verified round 1)
    const int*   vars    = (const int*)d_in[2];
    const float* factors = (const float*)d_in[3];
    float* out = (float*)d_out;

    if (ws_size >= (size_t)(NCH * BATCH) * sizeof(float)) {
        float* ws = (float*)d_ws;
        bmn_main<<<dim3(BATCH / G, NCH), NT, 0, stream>>>(x, vars, factors, ws, NCLS / NCH);
        bmn_reduce<<<1, BATCH, 0, stream>>>(ws, out);
    } else {
        // fallback: single chunk writes final sums directly (correct, slower)
        bmn_main<<<dim3(BATCH / G, 1), NT, 0, stream>>>(x, vars, factors, out, NCLS);
    }
}